// Round 3
// baseline (397.533 us; speedup 1.0000x reference)
//
#include <hip/hip_runtime.h>

// NW=32 wavelets, N=M=1024.
#define NPOINTS 1048576ULL
#define NWV 32

typedef _Float16 h8 __attribute__((ext_vector_type(8)));
typedef _Float16 h2 __attribute__((ext_vector_type(2)));
typedef float f32x4 __attribute__((ext_vector_type(4)));

// ---------------------------------------------------------------------------
// Compacted inverse-FFT twiddles, W_L^pos = exp(+2*pi*i*pos/L), L = 2^(hb+1).
// Stage hb (half = 2^hb): base = 1024 - 2^(hb+1), size 2^hb, hb = 9..2.
// ---------------------------------------------------------------------------
__global__ void k_init_tw(float2* __restrict__ tw) {
    int hb   = 9 - blockIdx.x;              // 9..2
    int cnt  = 1 << hb;
    int base = 1024 - (2 << hb);
    for (int pos = threadIdx.x; pos < cnt; pos += 256) {
        double ang = 6.283185307179586232 * (double)pos / (double)(2 << hb);
        tw[base + pos] = make_float2((float)cos(ang), (float)sin(ang));
    }
}

__device__ __forceinline__ void bf(float2& a, float2& b, float2 w) {
    float sx = a.x + b.x, sy = a.y + b.y;
    float dx = a.x - b.x, dy = a.y - b.y;
    a = make_float2(sx, sy);
    b = make_float2(dx * w.x - dy * w.y, dx * w.y + dy * w.x);
}

// One 1024-pt inverse DIF FFT per 64-lane wave (in: elem l+64k; out:
// bit-reversed-order slots — a consistent spatial permutation, Gram-safe).
__device__ __forceinline__ void wave_fft(float2* X, int l,
    const float2* __restrict__ twl, float* exr, float* exi)
{
    #pragma unroll
    for (int st = 0; st < 4; ++st) {        // half = 512,256,128,64
        const int step = 8 >> st;
        const float2* tb = twl + (1024 - (1024 >> st));
        #pragma unroll
        for (int g = 0; g < 16; g += 2 * step)
            #pragma unroll
            for (int c = 0; c < step; ++c)
                bf(X[g + c], X[g + c + step], tb[l + 64 * c]);
    }
    #pragma unroll
    for (int k = 0; k < 16; ++k) {          // SoA XOR-swizzled exchange
        int ph = 64 * k + (l ^ (k << 2));
        exr[ph] = X[k].x; exi[ph] = X[k].y;
    }
    __syncthreads();
    const int b = l >> 2, q = l & 3;
    float2 Y[16];
    #pragma unroll
    for (int j = 0; j < 16; ++j) {
        int ph = 64 * b + (((q + 4 * j) ^ (b << 2)) & 63);
        Y[j] = make_float2(exr[ph], exi[ph]);
    }
    #pragma unroll
    for (int st = 0; st < 4; ++st) {        // half = 32,16,8,4
        const int step = 8 >> st;
        const float2* tb = twl + (1024 - (64 >> st));
        #pragma unroll
        for (int g = 0; g < 16; g += 2 * step)
            #pragma unroll
            for (int c = 0; c < step; ++c)
                bf(Y[g + c], Y[g + c + step], tb[q + 4 * c]);
    }
    #pragma unroll
    for (int j = 0; j < 16; ++j) {          // half=2: lane^2, tw 1 / +i
        float ox = __shfl_xor(Y[j].x, 2);
        float oy = __shfl_xor(Y[j].y, 2);
        if ((l & 2) == 0) { Y[j].x += ox; Y[j].y += oy; }
        else {
            float dx = ox - Y[j].x, dy = oy - Y[j].y;
            Y[j] = (l & 1) ? make_float2(-dy, dx) : make_float2(dx, dy);
        }
    }
    #pragma unroll
    for (int j = 0; j < 16; ++j) {          // half=1: lane^1, tw 1
        float ox = __shfl_xor(Y[j].x, 1);
        float oy = __shfl_xor(Y[j].y, 1);
        if ((l & 1) == 0) { Y[j].x += ox; Y[j].y += oy; }
        else { Y[j].x = ox - Y[j].x; Y[j].y = oy - Y[j].y; }
    }
    #pragma unroll
    for (int j = 0; j < 16; ++j) X[j] = Y[j];
}

// ---------------------------------------------------------------------------
// Pass A: 8 waves/block = 8 rows of one wavelet. Pointwise complex multiply
// (scaled 1/2^20), wave FFT, block LDS transpose, write T[c][n] column-major.
// ---------------------------------------------------------------------------
__global__ __launch_bounds__(512, 4) void k_rowfft(
    const float2* __restrict__ xhat, const float* __restrict__ pre,
    const float* __restrict__ pim, const float2* __restrict__ twg,
    float2* __restrict__ T, int wbase)
{
    __shared__ float  ex[16448];      // 8 waves x 2 planes x 1028 floats
    __shared__ float2 twl[1020];
    const int t  = threadIdx.x;
    const int wv = t >> 6, l = t & 63;
    const int n  = blockIdx.x * 8 + wv;
    const int wl = blockIdx.y, w = wbase + wl;
    for (int i = t; i < 1020; i += 512) twl[i] = twg[i];
    float* exr = ex + wv * 2056;
    float* exi = exr + 1028;

    const float2* xr  = xhat + (size_t)n * 1024;
    const float*  prr = pre + (size_t)w * NPOINTS + (size_t)n * 1024;
    const float*  pir = pim + (size_t)w * NPOINTS + (size_t)n * 1024;
    float2 X[16];
    const float s = 1.0f / 1048576.0f;     // ifft2 1/(N*M)
    #pragma unroll
    for (int k = 0; k < 16; ++k) {
        float2 x = xr[l + 64 * k];
        float  a = prr[l + 64 * k], bb = pir[l + 64 * k];
        X[k] = make_float2((x.x * a - x.y * bb) * s, (x.y * a + x.x * bb) * s);
    }
    __syncthreads();                       // twiddles ready
    wave_fft(X, l, twl, exr, exi);

    const int b = l >> 2, q = l & 3;
    #pragma unroll
    for (int j = 0; j < 16; ++j) {
        int ph = 64 * b + (((q + 4 * j) ^ (b << 2)) & 63);
        exr[ph] = X[j].x; exi[ph] = X[j].y;
    }
    __syncthreads();
    float2* Tw = T + (size_t)wl * NPOINTS;
    const int n0 = blockIdx.x * 8;
    const int u = t >> 3, r = t & 7;
    const float* sr = ex + r * 2056;
    const float* si = sr + 1028;
    #pragma unroll
    for (int v = 0; v < 16; ++v) {
        int c  = v * 64 + u;
        int ph = v * 64 + (u ^ (v << 2));
        Tw[(size_t)c * 1024 + n0 + r] = make_float2(sr[ph], si[ph]);
    }
}

// ---------------------------------------------------------------------------
// Pass B: 8 waves/block = 8 columns. Coalesced column reads, wave FFT,
// modulus -> f16, packed h2 coalesced stores (re-permuted spatial order:
// slot = 128*q + 2*l + parity — consistent across wavelets, Gram-safe).
// ---------------------------------------------------------------------------
__global__ __launch_bounds__(512, 4) void k_colfft(
    const float2* __restrict__ T, const float2* __restrict__ twg,
    _Float16* __restrict__ modb, int wbase)
{
    __shared__ float  ex[16448];
    __shared__ float2 twl[1020];
    const int t  = threadIdx.x;
    const int wv = t >> 6, l = t & 63;
    const int c  = blockIdx.x * 8 + wv;
    const int wl = blockIdx.y, w = wbase + wl;
    for (int i = t; i < 1020; i += 512) twl[i] = twg[i];
    float* exr = ex + wv * 2056;
    float* exi = exr + 1028;

    const float2* Tc = T + (size_t)wl * NPOINTS + (size_t)c * 1024;
    float2 X[16];
    #pragma unroll
    for (int k = 0; k < 16; ++k) X[k] = Tc[64 * k + l];
    __syncthreads();                       // twiddles ready
    wave_fft(X, l, twl, exr, exi);

    _Float16* mo = modb + (size_t)w * NPOINTS + (size_t)c * 1024;
    #pragma unroll
    for (int q = 0; q < 8; ++q) {
        float m0 = sqrtf(X[2*q].x * X[2*q].x + X[2*q].y * X[2*q].y + 1e-8f);
        float m1 = sqrtf(X[2*q+1].x * X[2*q+1].x + X[2*q+1].y * X[2*q+1].y + 1e-8f);
        h2 v = { (_Float16)m0, (_Float16)m1 };
        *(h2*)&mo[2 * (q * 64 + l)] = v;
    }
}

// ---------------------------------------------------------------------------
// Pass C: Gram partials via MFMA. Block = 2048 points (4 tiles of 512);
// stage 32x512 f16 in LDS (+8 pad), each wave does its K-subset with
// mfma_f32_16x16x32_f16: c00 = A0*A0, c01 = A0*A1, c11 = A1*A1 (c10 = c01^T
// skipped; lower-left quadrant of part is never read).
// ---------------------------------------------------------------------------
__global__ __launch_bounds__(256) void k_gram(
    const _Float16* __restrict__ modb, float* __restrict__ part)
{
    __shared__ _Float16 tile[32][520];
    const int t = threadIdx.x;
    const int l = t & 63, wv = t >> 6;
    f32x4 c00 = {0.f,0.f,0.f,0.f}, c01 = {0.f,0.f,0.f,0.f}, c11 = {0.f,0.f,0.f,0.f};
    const size_t pbase = (size_t)blockIdx.x * 2048;

    for (int tt = 0; tt < 4; ++tt) {
        __syncthreads();
        size_t p0 = pbase + (size_t)tt * 512;
        #pragma unroll
        for (int i = 0; i < 8; ++i) {
            int w = i * 4 + wv;            // one full row per wave-instr
            *(h8*)&tile[w][(size_t)(l * 8)] =
                *(const h8*)&modb[((size_t)w << 20) + p0 + (size_t)(l * 8)];
        }
        __syncthreads();
        #pragma unroll
        for (int s = 0; s < 4; ++s) {
            int k0 = (s * 4 + wv) * 32 + ((l >> 4) * 8);
            h8 a0 = *(const h8*)&tile[l & 15][k0];
            h8 a1 = *(const h8*)&tile[16 + (l & 15)][k0];
            c00 = __builtin_amdgcn_mfma_f32_16x16x32_f16(a0, a0, c00, 0, 0, 0);
            c01 = __builtin_amdgcn_mfma_f32_16x16x32_f16(a0, a1, c01, 0, 0, 0);
            c11 = __builtin_amdgcn_mfma_f32_16x16x32_f16(a1, a1, c11, 0, 0, 0);
        }
    }
    const int row = (blockIdx.x << 2) | wv;     // 2048 partial rows
    float* pr = part + ((size_t)row << 10);
    #pragma unroll
    for (int r = 0; r < 4; ++r) {
        int i = (l >> 4) * 4 + r;    // C/D layout: col = l&15, row = (l>>4)*4+r
        int j = l & 15;
        pr[i * 32 + j]             = c00[r];
        pr[i * 32 + 16 + j]        = c01[r];
        pr[(16 + i) * 32 + 16 + j] = c11[r];
    }
}

// ---------------------------------------------------------------------------
// Pass D: fully-coalesced column reduce of part[2048][1024]; triangle map;
// einsum 1/(N*M) scale. Only upper-triangle slots are read/written.
// ---------------------------------------------------------------------------
__global__ __launch_bounds__(256) void k_reduce(
    const float* __restrict__ part, float* __restrict__ out)
{
    const int slot = blockIdx.x * 256 + threadIdx.x;   // 0..1023
    const int i = slot >> 5, j = slot & 31;
    float v = 0.0f;
    for (int r = 0; r < 2048; ++r)
        v += part[((size_t)r << 10) + slot];
    if (j >= i) {
        int q = 32 * i - (i * (i - 1)) / 2 + (j - i);
        if (q < 527) out[q] = v * (1.0f / 1048576.0f);
    }
}

// ---------------------------------------------------------------------------
extern "C" void kernel_launch(void* const* d_in, const int* in_sizes, int n_in,
                              void* d_out, int out_size, void* d_ws, size_t ws_size,
                              hipStream_t stream) {
    (void)in_sizes; (void)n_in; (void)out_size;
    const float2* xhat = (const float2*)d_in[0];
    const float*  pre  = (const float*)d_in[1];
    const float*  pim  = (const float*)d_in[2];
    float* out = (float*)d_out;

    char* ws = (char*)d_ws;
    float2*    tw   = (float2*)ws;                                  // 64 KB slot
    _Float16*  modb = (_Float16*)(ws + 65536);                      // 64 MB
    float*     part = (float*)(ws + 65536 + NWV * NPOINTS * 2ULL);  // 8 MB
    size_t     Toff = 65536 + NWV * NPOINTS * 2ULL + 2048ULL * 1024ULL * 4ULL;
    float2*    T    = (float2*)(ws + Toff);

    // T batched over wavelets; WB=8 (64 MB) keeps T L3-resident.
    int WB = 1;
    const int cands[4] = {8, 4, 2, 1};
    for (int c = 0; c < 4; ++c)
        if (Toff + (size_t)cands[c] * NPOINTS * 8ULL <= ws_size) { WB = cands[c]; break; }

    hipLaunchKernelGGL(k_init_tw, dim3(8), dim3(256), 0, stream, tw);
    for (int wb = 0; wb < NWV; wb += WB) {
        hipLaunchKernelGGL(k_rowfft, dim3(128, WB), dim3(512), 0, stream,
                           xhat, pre, pim, (const float2*)tw, T, wb);
        hipLaunchKernelGGL(k_colfft, dim3(128, WB), dim3(512), 0, stream,
                           (const float2*)T, (const float2*)tw, modb, wb);
    }
    hipLaunchKernelGGL(k_gram, dim3(512), dim3(256), 0, stream,
                       (const _Float16*)modb, part);
    hipLaunchKernelGGL(k_reduce, dim3(4), dim3(256), 0, stream,
                       (const float*)part, out);
}